// Round 9
// baseline (1434.114 us; speedup 1.0000x reference)
//
#include <hip/hip_runtime.h>
#include <cstdint>
#include <cstddef>

// ---------------- problem constants ----------------
#define NBATCH 8
#define MID 256
#define HIMG 64
#define WIMG 64
#define NA 9
#define NPRE 6000
#define NPOST 300
#define NANCH (HIMG*WIMG*NA)   // 36864
#define NWORDS 94              // ceil(6000/64)
#define GCOLS 6016             // 94*64 padded columns

// output float offsets
#define OUT_LOC   0
#define OUT_SCORE 1179648
#define OUT_ROIS  1769472
#define OUT_RIDX  1779072
#define OUT_ANCH  1781472

// workspace byte offsets
#define H_OFF    0ul
#define H_BYTES  (8ul*256*64*64*4)         // 33554432
#define WT_OFF   (H_OFF + H_BYTES)
#define WT_BYTES (2304ul*256*4)            // 2359296
#define BOX_OFF  (WT_OFF + WT_BYTES)
#define BOX_BYTES (8ul*36864*4*4)          // 4718592
#define U_OFF    (BOX_OFF + BOX_BYTES)
#define U_BYTES  (8ul*36864*4)
#define CK_OFF   (U_OFF + U_BYTES)
#define CK_BYTES (8ul*8192*8)
#define CC_OFF   (CK_OFF + CK_BYTES)
#define CC_BYTES 64ul
#define BK_OFF   (CC_OFF + CC_BYTES)
#define BK_BYTES (8ul*6000*16)
#define M_OFF    (BK_OFF + BK_BYTES + 64)
#define M_BYTES  (8ul*NWORDS*GCOLS*8)      // 36.2 MB, column-major mask
// gh (8x65536 u32 = 2 MB) and tiebuf (8x36864 u64 = 2.36 MB) ALIAS the MT region:
// they are written by anchors/hist16/select2 and dead before k_mask writes MT.
#define GH_OFF   M_OFF
#define TB_OFF   (M_OFF + 2097152ul)

// ---------------- weight transpose: w[oc][ic][ky][kx] -> wT[(ic*9+k)][oc] ----------------
__global__ void k_transpose_w(const float* __restrict__ w, float* __restrict__ wT) {
    int idx = blockIdx.x * 256 + threadIdx.x;   // 589824
    if (idx >= 589824) return;
    int oc = idx & 255;
    int rest = idx >> 8;              // ic*9 + k
    int ic = rest / 9, k = rest - ic * 9;
    wT[rest * 256 + oc] = w[(oc * 256 + ic) * 9 + k];
}

// ---------------- anchors output (exact double->f32 like numpy) + zero counters + zero gh ----------------
__global__ void k_anchors(float* __restrict__ out, unsigned int* __restrict__ cc,
                          unsigned int* __restrict__ gh) {
    int idx = blockIdx.x * 256 + threadIdx.x;   // grid 144 -> 36864 threads
    if (blockIdx.x == 0 && threadIdx.x < 16) cc[threadIdx.x] = 0u;
    for (unsigned int i = (unsigned int)idx; i < 524288u; i += 36864u) gh[i] = 0u;
    if (idx >= NANCH) return;
    int p = idx / 9, a = idx - p * 9;
    int y = p >> 6, xg = p & 63;
    double rr = (a < 3) ? 0.5 : ((a < 6) ? 1.0 : 2.0);
    int sj = a % 3;
    double ssc = (sj == 0) ? 8.0 : ((sj == 1) ? 16.0 : 32.0);
    double hh = 7.0 * ssc * sqrt(rr);
    double ww = 7.0 * ssc * sqrt(1.0 / rr);
    float a0 = (float)(3.5 - 0.5 * hh), a2 = (float)(3.5 + 0.5 * hh);
    float b0 = (float)(3.5 - 0.5 * ww), b2 = (float)(3.5 + 0.5 * ww);
    float* dst = out + OUT_ANCH + (size_t)idx * 4;
    dst[0] = y * 16.0f + a0;
    dst[1] = xg * 16.0f + b0;
    dst[2] = y * 16.0f + a2;
    dst[3] = xg * 16.0f + b2;
}

// ---------------- conv1 3x3 + bias + relu (fp32) — R8 measured-best, unchanged ----------------
__global__ __launch_bounds__(512) void k_conv1(const float* __restrict__ x,
                                               const float* __restrict__ wT,
                                               const float* __restrict__ bias,
                                               float* __restrict__ h) {
    __shared__ float in_t[8 * 18 * 35];   // 5040 floats: [ic][yy(18)][xx pitch 35]
    __shared__ float w_t[8 * 9 * 32];     // 2304 floats: [ic][k][oc32]
    const int tid = threadIdx.x;
    const int tile = blockIdx.x;          // 0..7 -> 4 y-tiles x 2 x-tiles
    const int octile = blockIdx.y;        // 0..7 (32 oc each)
    const int n = blockIdx.z;
    const int y0 = (tile >> 1) * 16, x0 = (tile & 1) * 32;
    const int s = tid & 63;               // lane
    const int w = tid >> 6;               // wave 0..7
    const int ocg = w & 3;                // wave-uniform: 8-oc group
    const int ph = w >> 2;                // wave-uniform: row half
    const int r = ph * 8 + (s >> 3);      // 0..15
    const int x0l = (s & 7) * 4;          // 0,4,...,28

    for (int i = tid; i < 5040; i += 512) in_t[i] = 0.f;

    float acc[8][4];
#pragma unroll
    for (int o = 0; o < 8; ++o)
#pragma unroll
        for (int j = 0; j < 4; ++j) acc[o][j] = 0.f;

    const float* xn = x + (size_t)n * 1048576;
    for (int ch = 0; ch < 32; ++ch) {
        const float* xb = xn + ch * 32768;
        const float* wb = wT + ch * 18432;
        __syncthreads();
        for (int idx = tid; idx < 4896; idx += 512) {
            int ic = idx / 612;
            int rem = idx - ic * 612;
            int yy = rem / 34, xx = rem - yy * 34;
            int gy = y0 - 1 + yy, gx = x0 - 1 + xx;
            if (gy >= 0 && gy < 64 && gx >= 0 && gx < 64)
                in_t[(ic * 18 + yy) * 35 + xx] = xb[ic * 4096 + gy * 64 + gx];
        }
        for (int idx = tid; idx < 2304; idx += 512) {
            int ocl = idx & 31;
            int kk = (idx >> 5) % 9;
            int ic = idx / 288;
            w_t[idx] = wb[((ic * 9 + kk) * 256) + octile * 32 + ocl];
        }
        __syncthreads();
#pragma unroll 1
        for (int ic = 0; ic < 8; ++ic) {
            float rowv[3][6];
            const float* bp = &in_t[(ic * 18 + r) * 35 + x0l];
#pragma unroll
            for (int ky = 0; ky < 3; ++ky)
#pragma unroll
                for (int m = 0; m < 6; ++m) rowv[ky][m] = bp[ky * 35 + m];
#pragma unroll
            for (int ky = 0; ky < 3; ++ky) {
#pragma unroll
                for (int kx = 0; kx < 3; ++kx) {
                    const float4* wp = (const float4*)&w_t[(ic * 9 + ky * 3 + kx) * 32 + ocg * 8];
                    float4 wa = wp[0], wb4 = wp[1];
                    float wv[8] = {wa.x, wa.y, wa.z, wa.w, wb4.x, wb4.y, wb4.z, wb4.w};
#pragma unroll
                    for (int o = 0; o < 8; ++o)
#pragma unroll
                        for (int j = 0; j < 4; ++j)
                            acc[o][j] = fmaf(rowv[ky][j + kx], wv[o], acc[o][j]);
                }
            }
        }
    }
    const int gy = y0 + r;
#pragma unroll
    for (int o = 0; o < 8; ++o) {
        int oc = octile * 32 + ocg * 8 + o;
        float bv = bias[oc];
        float4 v0;
        v0.x = fmaxf(acc[o][0] + bv, 0.f); v0.y = fmaxf(acc[o][1] + bv, 0.f);
        v0.z = fmaxf(acc[o][2] + bv, 0.f); v0.w = fmaxf(acc[o][3] + bv, 0.f);
        *(float4*)&h[((n * 256 + oc) * 64 + gy) * 64 + x0 + x0l] = v0;
    }
}

// ---------------- 1x1 heads + softmax fg + decode + sortable score ----------------
__global__ __launch_bounds__(256) void k_heads(const float* __restrict__ h,
                                               const float* __restrict__ loc_w,
                                               const float* __restrict__ score_w,
                                               const float* __restrict__ loc_b,
                                               const float* __restrict__ score_b,
                                               const int* __restrict__ ihp,
                                               const int* __restrict__ iwp,
                                               float* __restrict__ out,
                                               float* __restrict__ boxes,
                                               unsigned int* __restrict__ ubuf) {
    __shared__ float Wl[54 * 64];     // [c][kk]
    __shared__ float outb[128 * 57];  // [p][c] pitch 57
    const int tid = threadIdx.x;
    const int pl = tid & 127, chalf = tid >> 7;
    const int c0 = chalf * 27;
    const int ptile = blockIdx.x;
    const int n = blockIdx.y;
    const int pg = ptile * 128 + pl;

    float acc[27];
#pragma unroll
    for (int i = 0; i < 27; ++i) acc[i] = 0.f;

    for (int kc = 0; kc < 4; ++kc) {
        __syncthreads();
        for (int idx = tid; idx < 54 * 64; idx += 256) {
            int c = idx >> 6, kk = idx & 63;
            int gk = kc * 64 + kk;
            Wl[idx] = (c < 36) ? loc_w[c * 256 + gk] : score_w[(c - 36) * 256 + gk];
        }
        __syncthreads();
        for (int k4 = 0; k4 < 64; k4 += 4) {
            int gk = kc * 64 + k4;
            float hv0 = h[(n * 256 + gk + 0) * 4096 + pg];
            float hv1 = h[(n * 256 + gk + 1) * 4096 + pg];
            float hv2 = h[(n * 256 + gk + 2) * 4096 + pg];
            float hv3 = h[(n * 256 + gk + 3) * 4096 + pg];
#pragma unroll
            for (int ci = 0; ci < 27; ++ci) {
                float4 w4 = *(const float4*)&Wl[(c0 + ci) * 64 + k4];
                acc[ci] += hv0 * w4.x + hv1 * w4.y + hv2 * w4.z + hv3 * w4.w;
            }
        }
    }
#pragma unroll
    for (int ci = 0; ci < 27; ++ci) {
        int c = c0 + ci;
        float bv = (c < 36) ? loc_b[c] : score_b[c - 36];
        outb[pl * 57 + c] = acc[ci] + bv;
    }
    __syncthreads();

    const float fh = (float)(*ihp), fwid = (float)(*iwp);
    for (int slot = tid; slot < 128 * 9; slot += 256) {
        int pli = slot / 9, a = slot - pli * 9;
        int p = ptile * 128 + pli;
        int y = p >> 6, xg = p & 63;
        float l0 = outb[pli * 57 + a * 4 + 0];
        float l1 = outb[pli * 57 + a * 4 + 1];
        float l2 = outb[pli * 57 + a * 4 + 2];
        float l3 = outb[pli * 57 + a * 4 + 3];
        float s0 = outb[pli * 57 + 36 + a * 2 + 0];
        float s1 = outb[pli * 57 + 36 + a * 2 + 1];
        size_t base = (size_t)n * NANCH + (size_t)p * 9 + a;
        ((float4*)(out + OUT_LOC))[base] = make_float4(l0, l1, l2, l3);
        ((float2*)(out + OUT_SCORE))[base] = make_float2(s0, s1);
        float mx = fmaxf(s0, s1);
        float e0 = expf(s0 - mx), e1 = expf(s1 - mx);
        float fg = e1 / (e0 + e1);
        double rr = (a < 3) ? 0.5 : ((a < 6) ? 1.0 : 2.0);
        int sj = a % 3;
        double ssc = (sj == 0) ? 8.0 : ((sj == 1) ? 16.0 : 32.0);
        double hhd = 7.0 * ssc * sqrt(rr);
        double wwd = 7.0 * ssc * sqrt(1.0 / rr);
        float a0 = (float)(3.5 - 0.5 * hhd), a2 = (float)(3.5 + 0.5 * hhd);
        float b0 = (float)(3.5 - 0.5 * wwd), b2 = (float)(3.5 + 0.5 * wwd);
        float ay1 = y * 16.0f + a0, ay2 = y * 16.0f + a2;
        float ax1 = xg * 16.0f + b0, ax2 = xg * 16.0f + b2;
        float ah = ay2 - ay1, aw = ax2 - ax1;
        float acy = ay1 + 0.5f * ah, acx = ax1 + 0.5f * aw;
        float cy = l0 * ah + acy, cx = l1 * aw + acx;
        float bh = expf(l2) * ah, bw = expf(l3) * aw;
        float y1 = fminf(fmaxf(cy - 0.5f * bh, 0.f), fh);
        float x1 = fminf(fmaxf(cx - 0.5f * bw, 0.f), fwid);
        float y2 = fminf(fmaxf(cy + 0.5f * bh, 0.f), fh);
        float x2 = fminf(fmaxf(cx + 0.5f * bw, 0.f), fwid);
        ((float4*)boxes)[base] = make_float4(y1, x1, y2, x2);
        bool valid = ((y2 - y1) >= 16.0f) && ((x2 - x1) >= 16.0f);
        float sc = valid ? fg : -__builtin_inff();
        unsigned int ub = __float_as_uint(sc);
        ub = (ub & 0x80000000u) ? ~ub : (ub | 0x80000000u);
        ubuf[base] = ub;
    }
}

// ---------------- 16-bit histogram: one parallel data pass (128 blocks) ----------------
__global__ __launch_bounds__(256) void k_hist16(const unsigned int* __restrict__ ubuf,
                                                unsigned int* __restrict__ gh) {
    const int b = blockIdx.y;
    const int i0 = blockIdx.x * 2304;           // 16 sub-blocks x 2304 = 36864
    const unsigned int* ub = ubuf + (size_t)b * NANCH;
    unsigned int* g = gh + (size_t)b * 65536;
#pragma unroll
    for (int k = 0; k < 9; ++k) {
        unsigned int u = ub[i0 + k * 256 + threadIdx.x];
        atomicAdd(&g[u >> 16], 1u);
    }
}

// ---------------- exact top-6000: histogram cut + one compaction pass + exact tie fix ----------------
// Kept set bit-identical to the 4-pass radix version: all u > ustar plus all u == ustar,
// where ustar is the 6000th-largest u. Order canonicalized by k_sort.
__global__ __launch_bounds__(1024) void k_select2(const unsigned int* __restrict__ ubuf,
                                                  const unsigned int* __restrict__ gh,
                                                  unsigned long long* __restrict__ ckeys,
                                                  unsigned long long* __restrict__ tb,
                                                  unsigned int* __restrict__ cc) {
    __shared__ unsigned int psum[1024];
    __shared__ unsigned int cbins[64];
    __shared__ unsigned int sC, sM;
    __shared__ unsigned int lcnt, ntie;
    const int tid = threadIdx.x;
    const int b = blockIdx.x;
    const unsigned int* g = gh + (size_t)b * 65536;
    const unsigned int* ub = ubuf + (size_t)b * NANCH;
    unsigned long long* tbb = tb + (size_t)b * NANCH;
    if (tid == 0) { lcnt = 0u; ntie = 0u; }
    // phase A: descending 64-bin chunk sums (thread t owns bins (65535-64t) down)
    unsigned int s = 0;
    const int hi = 65535 - 64 * tid;
    for (int k = 0; k < 64; ++k) s += g[hi - k];
    psum[tid] = s;
    __syncthreads();
    if (tid == 0) {
        unsigned int cum = 0; int owner = 1023;
        for (int t = 0; t < 1024; ++t) {
            if (cum + psum[t] > 5999u) { owner = t; break; }
            cum += psum[t];
        }
        psum[0] = (unsigned int)owner; psum[1] = cum;
    }
    __syncthreads();
    const int owner = (int)psum[0];
    const unsigned int baseCum = psum[1];
    const int hio = 65535 - 64 * owner;
    if (tid < 64) cbins[tid] = g[hio - tid];
    __syncthreads();
    if (tid == 0) {
        unsigned int cum = baseCum, C = (unsigned int)(hio - 63), M = 0;
        for (int k = 0; k < 64; ++k) {
            unsigned int c2 = cbins[k];
            if (cum + c2 > 5999u) { C = (unsigned int)(hio - k); M = 5999u - cum; break; }
            cum += c2;
        }
        sC = C; sM = M;
    }
    __syncthreads();
    const unsigned int C = sC, M = sM;
    // phase B: single compaction pass
    for (int i = tid; i < NANCH; i += 1024) {
        unsigned int u = ub[i];
        unsigned int t16 = u >> 16;
        unsigned long long key =
            ((unsigned long long)u << 32) | (unsigned int)(0xFFFFFFFFu - (unsigned int)i);
        if (t16 > C) {
            unsigned int pos = atomicAdd(&lcnt, 1u);
            if (pos < 8192u) ckeys[(size_t)b * 8192 + pos] = key;
        } else if (t16 == C) {
            unsigned int p2 = atomicAdd(&ntie, 1u);
            tbb[p2] = key;
        }
    }
    __syncthreads();
    // phase C: exact tie resolution within bin C (keep iff #{u_j > u_e} <= M  <=>  u_e >= ustar)
    const int nt = (int)ntie;
    for (int e = tid; e < nt; e += 1024) {
        unsigned long long my = tbb[e];
        unsigned int myu = (unsigned int)(my >> 32);
        unsigned int cg = 0;
        for (int j = 0; j < nt; ++j)
            cg += ((unsigned int)(tbb[j] >> 32) > myu) ? 1u : 0u;
        if (cg <= M) {
            unsigned int pos = atomicAdd(&lcnt, 1u);
            if (pos < 8192u) ckeys[(size_t)b * 8192 + pos] = my;
        }
    }
    __syncthreads();
    if (tid == 0) cc[b] = (lcnt > 8192u) ? 8192u : lcnt;
}

// ---------------- bitonic sort 8192 composite keys + gather boxes ----------------
__global__ __launch_bounds__(1024) void k_sort(const unsigned long long* __restrict__ ckeys,
                                               const unsigned int* __restrict__ cc,
                                               const float* __restrict__ boxes,
                                               float* __restrict__ bk) {
    __shared__ unsigned long long S[8192];
    const int tid = threadIdx.x;
    const int b = blockIdx.x;
    const int cnt = (int)cc[b];
    for (int i = tid; i < 8192; i += 1024)
        S[i] = (i < cnt) ? ckeys[(size_t)b * 8192 + i] : 0ull;
    __syncthreads();
    for (int k = 2; k <= 8192; k <<= 1) {
        for (int j = k >> 1; j > 0; j >>= 1) {
            for (int i = tid; i < 8192; i += 1024) {
                int l = i ^ j;
                if (l > i) {
                    unsigned long long av = S[i], cv = S[l];
                    bool desc = ((i & k) == 0);
                    bool sw = desc ? (av < cv) : (av > cv);
                    if (sw) { S[i] = cv; S[l] = av; }
                }
            }
            __syncthreads();
        }
    }
    for (int i = tid; i < NPRE; i += 1024) {
        unsigned long long key = S[i];
        unsigned int idx = 0xFFFFFFFFu - (unsigned int)(key & 0xFFFFFFFFull);
        if (idx >= NANCH) idx = NANCH - 1;   // safety
        float4 bx = ((const float4*)boxes)[(size_t)b * NANCH + idx];
        ((float4*)bk)[(size_t)b * NPRE + i] = bx;
    }
}

// ---------------- IoU bitmask, COLUMN-major (guarded store) ----------------
__global__ __launch_bounds__(256) void k_mask(const float* __restrict__ bk,
                                              unsigned long long* __restrict__ MT) {
    const int iw = blockIdx.x;
    const int gb = blockIdx.y;
    const int b = blockIdx.z;
    if (iw > 4 * gb + 3) return;
    const int tid = threadIdx.x;
    __shared__ float4 jb[64];
    if (tid < 64) {
        int j = iw * 64 + tid;
        jb[tid] = (j < NPRE) ? ((const float4*)bk)[(size_t)b * NPRE + j]
                             : make_float4(0.f, 0.f, 0.f, 0.f);
    }
    __syncthreads();
    const int g = gb * 256 + tid;
    float4 bi = (g < NPRE) ? ((const float4*)bk)[(size_t)b * NPRE + g]
                           : make_float4(0.f, 0.f, 0.f, 0.f);
    float ai = (bi.z - bi.x) * (bi.w - bi.y);
    unsigned long long word = 0ull;
#pragma unroll 4
    for (int jj = 0; jj < 64; ++jj) {
        float4 bj = jb[jj];
        float ty = fmaxf(bi.x, bj.x), tx = fmaxf(bi.y, bj.y);
        float by = fminf(bi.z, bj.z), bx = fminf(bi.w, bj.w);
        float ihh = fmaxf(by - ty, 0.f), iww = fmaxf(bx - tx, 0.f);
        float inter = ihh * iww;
        float aj = (bj.z - bj.x) * (bj.w - bj.y);
        float iou = inter / (ai + aj - inter + 1e-9f);
        if (iou > 0.7f) word |= (1ull << jj);
    }
    if (g < GCOLS)
        MT[((size_t)b * NWORDS + iw) * GCOLS + g] = word;
}

// ---------------- greedy NMS: incremental PUSH model, 16 waves per batch ----------------
__global__ __launch_bounds__(1024) void k_nms(const unsigned long long* __restrict__ MT,
                                              const float* __restrict__ bk,
                                              float* __restrict__ out) {
    const int b = blockIdx.x;
    const int tid = threadIdx.x;
    const int lane = tid & 63;
    __shared__ unsigned long long keptw[NWORDS];
    __shared__ unsigned long long dead[NWORDS];
    __shared__ int sel[NPOST];
    const unsigned long long* mtb = MT + (size_t)b * NWORDS * GCOLS;

    for (int i = tid; i < NWORDS; i += 1024) { dead[i] = 0ull; keptw[i] = 0ull; }
    __syncthreads();

    for (int c = 0; c < NWORDS; ++c) {
        if (tid < 64) {
            const int g = c * 64 + lane;
            unsigned long long diag = mtb[(size_t)c * GCOLS + g];
            bool deadl = (((dead[c] >> lane) & 1ull) != 0ull) || (g >= NPRE);
            unsigned long long undec = ~__ballot(deadl);
            unsigned long long kc = 0ull;
            while (undec) {
                int i = __builtin_ctzll(undec);
                kc |= (1ull << i);
                unsigned long long supm = __ballot((diag >> i) & 1ull);
                undec &= ~(supm | (1ull << i));
            }
            if (lane == 0) keptw[c] = kc;
        }
        __syncthreads();
        const unsigned long long kc = keptw[c];
        if (kc) {
            for (int g2 = (c + 1) * 64 + tid; g2 < GCOLS; g2 += 1024) {
                unsigned long long w = mtb[(size_t)c * GCOLS + g2] & kc;
                unsigned long long m = __ballot(w != 0ull);
                if (lane == 0 && m) atomicOr(&dead[g2 >> 6], m);
            }
        }
        __syncthreads();
    }

    if (tid == 0) {
        int pos = 0;
        for (int w = 0; w < NWORDS && pos < NPOST; ++w) {
            unsigned long long kw = keptw[w];
            while (kw && pos < NPOST) {
                int i2 = __builtin_ctzll(kw);
                sel[pos++] = w * 64 + i2;
                kw &= kw - 1;
            }
        }
        for (int w = 0; w < NWORDS && pos < NPOST; ++w) {
            int nvalid = NPRE - w * 64; if (nvalid > 64) nvalid = 64;
            unsigned long long vm = (nvalid >= 64) ? ~0ull : ((1ull << nvalid) - 1ull);
            unsigned long long sw = (~keptw[w]) & vm;
            while (sw && pos < NPOST) {
                int i2 = __builtin_ctzll(sw);
                sel[pos++] = w * 64 + i2;
                sw &= sw - 1;
            }
        }
    }
    __syncthreads();
    for (int s2 = tid; s2 < NPOST; s2 += 1024) {
        int i = sel[s2];
        float4 bx = ((const float4*)bk)[(size_t)b * NPRE + i];
        ((float4*)(out + OUT_ROIS))[b * NPOST + s2] = bx;
        out[OUT_RIDX + b * NPOST + s2] = (float)b;
    }
}

// ---------------- launch ----------------
extern "C" void kernel_launch(void* const* d_in, const int* in_sizes, int n_in,
                              void* d_out, int out_size, void* d_ws, size_t ws_size,
                              hipStream_t stream) {
    const float* x = (const float*)d_in[0];
    const float* conv1_w = (const float*)d_in[1];
    const float* conv1_b = (const float*)d_in[2];
    const float* score_w = (const float*)d_in[3];
    const float* score_b = (const float*)d_in[4];
    const float* loc_w = (const float*)d_in[5];
    const float* loc_b = (const float*)d_in[6];
    const int* ihp = (const int*)d_in[7];
    const int* iwp = (const int*)d_in[8];
    float* out = (float*)d_out;
    char* ws = (char*)d_ws;
    float* h = (float*)(ws + H_OFF);
    float* wT = (float*)(ws + WT_OFF);
    float* boxes = (float*)(ws + BOX_OFF);
    unsigned int* ubuf = (unsigned int*)(ws + U_OFF);
    unsigned long long* ckeys = (unsigned long long*)(ws + CK_OFF);
    unsigned int* cc = (unsigned int*)(ws + CC_OFF);
    float* bk = (float*)(ws + BK_OFF);
    unsigned long long* MT = (unsigned long long*)(ws + M_OFF);
    unsigned int* gh = (unsigned int*)(ws + GH_OFF);          // aliases MT (dead before k_mask)
    unsigned long long* tb = (unsigned long long*)(ws + TB_OFF);

    hipLaunchKernelGGL(k_transpose_w, dim3(2304), dim3(256), 0, stream, conv1_w, wT);
    hipLaunchKernelGGL(k_anchors, dim3(144), dim3(256), 0, stream, out, cc, gh);
    hipLaunchKernelGGL(k_conv1, dim3(8, 8, 8), dim3(512), 0, stream, x, wT, conv1_b, h);
    hipLaunchKernelGGL(k_heads, dim3(32, 8), dim3(256), 0, stream,
                       h, loc_w, score_w, loc_b, score_b, ihp, iwp, out, boxes, ubuf);
    hipLaunchKernelGGL(k_hist16, dim3(16, 8), dim3(256), 0, stream, ubuf, gh);
    hipLaunchKernelGGL(k_select2, dim3(8), dim3(1024), 0, stream, ubuf, gh, ckeys, tb, cc);
    hipLaunchKernelGGL(k_sort, dim3(8), dim3(1024), 0, stream, ckeys, cc, boxes, bk);
    hipLaunchKernelGGL(k_mask, dim3(94, 24, 8), dim3(256), 0, stream, bk, MT);
    hipLaunchKernelGGL(k_nms, dim3(8), dim3(1024), 0, stream, MT, bk, out);
}

// Round 11
// 1081.077 us; speedup vs baseline: 1.3266x; 1.3266x over previous
//
#include <hip/hip_runtime.h>
#include <cstdint>
#include <cstddef>

// ---------------- problem constants ----------------
#define NBATCH 8
#define MID 256
#define HIMG 64
#define WIMG 64
#define NA 9
#define NPRE 6000
#define NPOST 300
#define NANCH (HIMG*WIMG*NA)   // 36864
#define NWORDS 94              // ceil(6000/64)
#define GCOLS 6016             // 94*64 padded columns

// output float offsets
#define OUT_LOC   0
#define OUT_SCORE 1179648
#define OUT_ROIS  1769472
#define OUT_RIDX  1779072
#define OUT_ANCH  1781472

// workspace byte offsets
#define H_OFF    0ul
#define H_BYTES  (8ul*256*64*64*4)         // 33554432
#define WT_OFF   (H_OFF + H_BYTES)
#define WT_BYTES (2304ul*256*4)            // 2359296
#define BOX_OFF  (WT_OFF + WT_BYTES)
#define BOX_BYTES (8ul*36864*4*4)          // 4718592
#define U_OFF    (BOX_OFF + BOX_BYTES)
#define U_BYTES  (8ul*36864*4)
#define CK_OFF   (U_OFF + U_BYTES)
#define CK_BYTES (8ul*8192*8)
#define CC_OFF   (CK_OFF + CK_BYTES)
#define CC_BYTES 64ul
#define BK_OFF   (CC_OFF + CC_BYTES)
#define BK_BYTES (8ul*6000*16)
#define M_OFF    (BK_OFF + BK_BYTES + 64)
#define M_BYTES  (8ul*NWORDS*GCOLS*8)      // 36.2 MB, column-major mask

// ---------------- weight transpose: w[oc][ic][ky][kx] -> wT[(ic*9+k)][oc] ----------------
__global__ void k_transpose_w(const float* __restrict__ w, float* __restrict__ wT) {
    int idx = blockIdx.x * 256 + threadIdx.x;   // 589824
    if (idx >= 589824) return;
    int oc = idx & 255;
    int rest = idx >> 8;              // ic*9 + k
    int ic = rest / 9, k = rest - ic * 9;
    wT[rest * 256 + oc] = w[(oc * 256 + ic) * 9 + k];
}

// ---------------- anchors output (exact double->f32 like numpy) + zero counters ----------------
__global__ void k_anchors(float* __restrict__ out, unsigned int* __restrict__ cc) {
    int idx = blockIdx.x * 256 + threadIdx.x;
    if (blockIdx.x == 0 && threadIdx.x < 16) cc[threadIdx.x] = 0u;
    if (idx >= NANCH) return;
    int p = idx / 9, a = idx - p * 9;
    int y = p >> 6, xg = p & 63;
    double rr = (a < 3) ? 0.5 : ((a < 6) ? 1.0 : 2.0);
    int sj = a % 3;
    double ssc = (sj == 0) ? 8.0 : ((sj == 1) ? 16.0 : 32.0);
    double hh = 7.0 * ssc * sqrt(rr);
    double ww = 7.0 * ssc * sqrt(1.0 / rr);
    float a0 = (float)(3.5 - 0.5 * hh), a2 = (float)(3.5 + 0.5 * hh);
    float b0 = (float)(3.5 - 0.5 * ww), b2 = (float)(3.5 + 0.5 * ww);
    float* dst = out + OUT_ANCH + (size_t)idx * 4;
    dst[0] = y * 16.0f + a0;
    dst[1] = xg * 16.0f + b0;
    dst[2] = y * 16.0f + a2;
    dst[3] = xg * 16.0f + b2;
}

// ---------------- conv1 3x3 + bias + relu (fp32) — R8 measured-best, unchanged ----------------
__global__ __launch_bounds__(512) void k_conv1(const float* __restrict__ x,
                                               const float* __restrict__ wT,
                                               const float* __restrict__ bias,
                                               float* __restrict__ h) {
    __shared__ float in_t[8 * 18 * 35];   // 5040 floats: [ic][yy(18)][xx pitch 35]
    __shared__ float w_t[8 * 9 * 32];     // 2304 floats: [ic][k][oc32]
    const int tid = threadIdx.x;
    const int tile = blockIdx.x;          // 0..7 -> 4 y-tiles x 2 x-tiles
    const int octile = blockIdx.y;        // 0..7 (32 oc each)
    const int n = blockIdx.z;
    const int y0 = (tile >> 1) * 16, x0 = (tile & 1) * 32;
    const int s = tid & 63;               // lane
    const int w = tid >> 6;               // wave 0..7
    const int ocg = w & 3;                // wave-uniform: 8-oc group
    const int ph = w >> 2;                // wave-uniform: row half
    const int r = ph * 8 + (s >> 3);      // 0..15
    const int x0l = (s & 7) * 4;          // 0,4,...,28

    for (int i = tid; i < 5040; i += 512) in_t[i] = 0.f;

    float acc[8][4];
#pragma unroll
    for (int o = 0; o < 8; ++o)
#pragma unroll
        for (int j = 0; j < 4; ++j) acc[o][j] = 0.f;

    const float* xn = x + (size_t)n * 1048576;
    for (int ch = 0; ch < 32; ++ch) {
        const float* xb = xn + ch * 32768;
        const float* wb = wT + ch * 18432;
        __syncthreads();
        for (int idx = tid; idx < 4896; idx += 512) {
            int ic = idx / 612;
            int rem = idx - ic * 612;
            int yy = rem / 34, xx = rem - yy * 34;
            int gy = y0 - 1 + yy, gx = x0 - 1 + xx;
            if (gy >= 0 && gy < 64 && gx >= 0 && gx < 64)
                in_t[(ic * 18 + yy) * 35 + xx] = xb[ic * 4096 + gy * 64 + gx];
        }
        for (int idx = tid; idx < 2304; idx += 512) {
            int ocl = idx & 31;
            int kk = (idx >> 5) % 9;
            int ic = idx / 288;
            w_t[idx] = wb[((ic * 9 + kk) * 256) + octile * 32 + ocl];
        }
        __syncthreads();
#pragma unroll 1
        for (int ic = 0; ic < 8; ++ic) {
            float rowv[3][6];
            const float* bp = &in_t[(ic * 18 + r) * 35 + x0l];
#pragma unroll
            for (int ky = 0; ky < 3; ++ky)
#pragma unroll
                for (int m = 0; m < 6; ++m) rowv[ky][m] = bp[ky * 35 + m];
#pragma unroll
            for (int ky = 0; ky < 3; ++ky) {
#pragma unroll
                for (int kx = 0; kx < 3; ++kx) {
                    const float4* wp = (const float4*)&w_t[(ic * 9 + ky * 3 + kx) * 32 + ocg * 8];
                    float4 wa = wp[0], wb4 = wp[1];
                    float wv[8] = {wa.x, wa.y, wa.z, wa.w, wb4.x, wb4.y, wb4.z, wb4.w};
#pragma unroll
                    for (int o = 0; o < 8; ++o)
#pragma unroll
                        for (int j = 0; j < 4; ++j)
                            acc[o][j] = fmaf(rowv[ky][j + kx], wv[o], acc[o][j]);
                }
            }
        }
    }
    const int gy = y0 + r;
#pragma unroll
    for (int o = 0; o < 8; ++o) {
        int oc = octile * 32 + ocg * 8 + o;
        float bv = bias[oc];
        float4 v0;
        v0.x = fmaxf(acc[o][0] + bv, 0.f); v0.y = fmaxf(acc[o][1] + bv, 0.f);
        v0.z = fmaxf(acc[o][2] + bv, 0.f); v0.w = fmaxf(acc[o][3] + bv, 0.f);
        *(float4*)&h[((n * 256 + oc) * 64 + gy) * 64 + x0 + x0l] = v0;
    }
}

// ---------------- 1x1 heads — EXACT R9 v1 (passing binary's structure; FP untouched) ----------------
__global__ __launch_bounds__(256) void k_heads(const float* __restrict__ h,
                                               const float* __restrict__ loc_w,
                                               const float* __restrict__ score_w,
                                               const float* __restrict__ loc_b,
                                               const float* __restrict__ score_b,
                                               const int* __restrict__ ihp,
                                               const int* __restrict__ iwp,
                                               float* __restrict__ out,
                                               float* __restrict__ boxes,
                                               unsigned int* __restrict__ ubuf) {
    __shared__ float Wl[54 * 64];     // [c][kk]
    __shared__ float outb[128 * 57];  // [p][c] pitch 57
    const int tid = threadIdx.x;
    const int pl = tid & 127, chalf = tid >> 7;
    const int c0 = chalf * 27;
    const int ptile = blockIdx.x;
    const int n = blockIdx.y;
    const int pg = ptile * 128 + pl;

    float acc[27];
#pragma unroll
    for (int i = 0; i < 27; ++i) acc[i] = 0.f;

    for (int kc = 0; kc < 4; ++kc) {
        __syncthreads();
        for (int idx = tid; idx < 54 * 64; idx += 256) {
            int c = idx >> 6, kk = idx & 63;
            int gk = kc * 64 + kk;
            Wl[idx] = (c < 36) ? loc_w[c * 256 + gk] : score_w[(c - 36) * 256 + gk];
        }
        __syncthreads();
        for (int k4 = 0; k4 < 64; k4 += 4) {
            int gk = kc * 64 + k4;
            float hv0 = h[(n * 256 + gk + 0) * 4096 + pg];
            float hv1 = h[(n * 256 + gk + 1) * 4096 + pg];
            float hv2 = h[(n * 256 + gk + 2) * 4096 + pg];
            float hv3 = h[(n * 256 + gk + 3) * 4096 + pg];
#pragma unroll
            for (int ci = 0; ci < 27; ++ci) {
                float4 w4 = *(const float4*)&Wl[(c0 + ci) * 64 + k4];
                acc[ci] += hv0 * w4.x + hv1 * w4.y + hv2 * w4.z + hv3 * w4.w;
            }
        }
    }
#pragma unroll
    for (int ci = 0; ci < 27; ++ci) {
        int c = c0 + ci;
        float bv = (c < 36) ? loc_b[c] : score_b[c - 36];
        outb[pl * 57 + c] = acc[ci] + bv;
    }
    __syncthreads();

    const float fh = (float)(*ihp), fwid = (float)(*iwp);
    for (int slot = tid; slot < 128 * 9; slot += 256) {
        int pli = slot / 9, a = slot - pli * 9;
        int p = ptile * 128 + pli;
        int y = p >> 6, xg = p & 63;
        float l0 = outb[pli * 57 + a * 4 + 0];
        float l1 = outb[pli * 57 + a * 4 + 1];
        float l2 = outb[pli * 57 + a * 4 + 2];
        float l3 = outb[pli * 57 + a * 4 + 3];
        float s0 = outb[pli * 57 + 36 + a * 2 + 0];
        float s1 = outb[pli * 57 + 36 + a * 2 + 1];
        size_t base = (size_t)n * NANCH + (size_t)p * 9 + a;
        ((float4*)(out + OUT_LOC))[base] = make_float4(l0, l1, l2, l3);
        ((float2*)(out + OUT_SCORE))[base] = make_float2(s0, s1);
        float mx = fmaxf(s0, s1);
        float e0 = expf(s0 - mx), e1 = expf(s1 - mx);
        float fg = e1 / (e0 + e1);
        double rr = (a < 3) ? 0.5 : ((a < 6) ? 1.0 : 2.0);
        int sj = a % 3;
        double ssc = (sj == 0) ? 8.0 : ((sj == 1) ? 16.0 : 32.0);
        double hhd = 7.0 * ssc * sqrt(rr);
        double wwd = 7.0 * ssc * sqrt(1.0 / rr);
        float a0 = (float)(3.5 - 0.5 * hhd), a2 = (float)(3.5 + 0.5 * hhd);
        float b0 = (float)(3.5 - 0.5 * wwd), b2 = (float)(3.5 + 0.5 * wwd);
        float ay1 = y * 16.0f + a0, ay2 = y * 16.0f + a2;
        float ax1 = xg * 16.0f + b0, ax2 = xg * 16.0f + b2;
        float ah = ay2 - ay1, aw = ax2 - ax1;
        float acy = ay1 + 0.5f * ah, acx = ax1 + 0.5f * aw;
        float cy = l0 * ah + acy, cx = l1 * aw + acx;
        float bh = expf(l2) * ah, bw = expf(l3) * aw;
        float y1 = fminf(fmaxf(cy - 0.5f * bh, 0.f), fh);
        float x1 = fminf(fmaxf(cx - 0.5f * bw, 0.f), fwid);
        float y2 = fminf(fmaxf(cy + 0.5f * bh, 0.f), fh);
        float x2 = fminf(fmaxf(cx + 0.5f * bw, 0.f), fwid);
        ((float4*)boxes)[base] = make_float4(y1, x1, y2, x2);
        bool valid = ((y2 - y1) >= 16.0f) && ((x2 - x1) >= 16.0f);
        float sc = valid ? fg : -__builtin_inff();
        unsigned int ub = __float_as_uint(sc);
        ub = (ub & 0x80000000u) ? ~ub : (ub | 0x80000000u);
        ubuf[base] = ub;
    }
}

// ---------------- exact top-6000 per batch: byte-radix select + compact (R8 measured-best) ----------------
__global__ __launch_bounds__(1024) void k_select(const unsigned int* __restrict__ ubuf,
                                                 unsigned long long* __restrict__ ckeys,
                                                 unsigned int* __restrict__ cc) {
    __shared__ unsigned int hist[256];
    __shared__ unsigned int selb;
    __shared__ int rank_s;
    __shared__ unsigned int lcnt;
    const int tid = threadIdx.x;
    const int b = blockIdx.x;
    const unsigned int* ub = ubuf + (size_t)b * NANCH;
    if (tid == 0) { rank_s = NPRE - 1; lcnt = 0; }
    unsigned int prefix = 0;
    for (int pass = 0; pass < 4; ++pass) {
        int shift = 24 - 8 * pass;
        if (tid < 256) hist[tid] = 0;
        __syncthreads();
        for (int i = tid; i < NANCH; i += 1024) {
            unsigned int u = ub[i];
            bool ok = (pass == 0) || ((u >> (shift + 8)) == (prefix >> (shift + 8)));
            if (ok) atomicAdd(&hist[(u >> shift) & 255], 1u);
        }
        __syncthreads();
        if (tid == 0) {
            int racc = 0; unsigned int bs = 0; int r = rank_s;
            for (int bb = 255; bb >= 0; --bb) {
                int c = (int)hist[bb];
                if (racc + c > r) { bs = (unsigned int)bb; rank_s = r - racc; break; }
                racc += c;
            }
            selb = bs;
        }
        __syncthreads();
        prefix |= (selb << shift);
        __syncthreads();
    }
    const unsigned int ustar = prefix;
    for (int i = tid; i < NANCH; i += 1024) {
        unsigned int u = ub[i];
        if (u >= ustar) {
            unsigned int pos = atomicAdd(&lcnt, 1u);
            if (pos < 8192)
                ckeys[(size_t)b * 8192 + pos] =
                    ((unsigned long long)u << 32) | (unsigned int)(0xFFFFFFFFu - (unsigned int)i);
        }
    }
    __syncthreads();
    if (tid == 0) cc[b] = (lcnt > 8192u) ? 8192u : lcnt;
}

// ---------------- bitonic sort 8192 composite keys + gather boxes ----------------
__global__ __launch_bounds__(1024) void k_sort(const unsigned long long* __restrict__ ckeys,
                                               const unsigned int* __restrict__ cc,
                                               const float* __restrict__ boxes,
                                               float* __restrict__ bk) {
    __shared__ unsigned long long S[8192];
    const int tid = threadIdx.x;
    const int b = blockIdx.x;
    const int cnt = (int)cc[b];
    for (int i = tid; i < 8192; i += 1024)
        S[i] = (i < cnt) ? ckeys[(size_t)b * 8192 + i] : 0ull;
    __syncthreads();
    for (int k = 2; k <= 8192; k <<= 1) {
        for (int j = k >> 1; j > 0; j >>= 1) {
            for (int i = tid; i < 8192; i += 1024) {
                int l = i ^ j;
                if (l > i) {
                    unsigned long long av = S[i], cv = S[l];
                    bool desc = ((i & k) == 0);
                    bool sw = desc ? (av < cv) : (av > cv);
                    if (sw) { S[i] = cv; S[l] = av; }
                }
            }
            __syncthreads();
        }
    }
    for (int i = tid; i < NPRE; i += 1024) {
        unsigned long long key = S[i];
        unsigned int idx = 0xFFFFFFFFu - (unsigned int)(key & 0xFFFFFFFFull);
        if (idx >= NANCH) idx = NANCH - 1;   // safety
        float4 bx = ((const float4*)boxes)[(size_t)b * NANCH + idx];
        ((float4*)bk)[(size_t)b * NPRE + i] = bx;
    }
}

// ---------------- IoU bitmask, COLUMN-major (guarded store) ----------------
__global__ __launch_bounds__(256) void k_mask(const float* __restrict__ bk,
                                              unsigned long long* __restrict__ MT) {
    const int iw = blockIdx.x;
    const int gb = blockIdx.y;
    const int b = blockIdx.z;
    if (iw > 4 * gb + 3) return;
    const int tid = threadIdx.x;
    __shared__ float4 jb[64];
    if (tid < 64) {
        int j = iw * 64 + tid;
        jb[tid] = (j < NPRE) ? ((const float4*)bk)[(size_t)b * NPRE + j]
                             : make_float4(0.f, 0.f, 0.f, 0.f);
    }
    __syncthreads();
    const int g = gb * 256 + tid;
    float4 bi = (g < NPRE) ? ((const float4*)bk)[(size_t)b * NPRE + g]
                           : make_float4(0.f, 0.f, 0.f, 0.f);
    float ai = (bi.z - bi.x) * (bi.w - bi.y);
    unsigned long long word = 0ull;
#pragma unroll 4
    for (int jj = 0; jj < 64; ++jj) {
        float4 bj = jb[jj];
        float ty = fmaxf(bi.x, bj.x), tx = fmaxf(bi.y, bj.y);
        float by = fminf(bi.z, bj.z), bx = fminf(bi.w, bj.w);
        float ihh = fmaxf(by - ty, 0.f), iww = fmaxf(bx - tx, 0.f);
        float inter = ihh * iww;
        float aj = (bj.z - bj.x) * (bj.w - bj.y);
        float iou = inter / (ai + aj - inter + 1e-9f);
        if (iou > 0.7f) word |= (1ull << jj);
    }
    if (g < GCOLS)
        MT[((size_t)b * NWORDS + iw) * GCOLS + g] = word;
}

// ---------------- greedy NMS: push model + EARLY BREAK at >=300 kept (single R10 change kept) ----------------
// Kept decisions for chunk c depend only on chunks < c; once cumulative kept >= 300,
// later chunks cannot affect the first-300 output. keptw[] pre-zeroed keeps sel-build valid.
__global__ __launch_bounds__(1024) void k_nms(const unsigned long long* __restrict__ MT,
                                              const float* __restrict__ bk,
                                              float* __restrict__ out) {
    const int b = blockIdx.x;
    const int tid = threadIdx.x;
    const int lane = tid & 63;
    __shared__ unsigned long long keptw[NWORDS];
    __shared__ unsigned long long dead[NWORDS];
    __shared__ int sel[NPOST];
    __shared__ int totkept;
    const unsigned long long* mtb = MT + (size_t)b * NWORDS * GCOLS;

    for (int i = tid; i < NWORDS; i += 1024) { dead[i] = 0ull; keptw[i] = 0ull; }
    if (tid == 0) totkept = 0;
    __syncthreads();

    for (int c = 0; c < NWORDS; ++c) {
        if (tid < 64) {   // wave 0: in-chunk greedy closure
            const int g = c * 64 + lane;
            unsigned long long diag = mtb[(size_t)c * GCOLS + g];
            bool deadl = (((dead[c] >> lane) & 1ull) != 0ull) || (g >= NPRE);
            unsigned long long undec = ~__ballot(deadl);
            unsigned long long kc = 0ull;
            while (undec) {
                int i = __builtin_ctzll(undec);
                kc |= (1ull << i);
                unsigned long long supm = __ballot((diag >> i) & 1ull);
                undec &= ~(supm | (1ull << i));
            }
            if (lane == 0) { keptw[c] = kc; totkept += __popcll(kc); }
        }
        __syncthreads();
        if (totkept >= NPOST) break;          // later chunks can't affect the output
        const unsigned long long kc = keptw[c];
        if (kc) {
            for (int g2 = (c + 1) * 64 + tid; g2 < GCOLS; g2 += 1024) {
                unsigned long long w = mtb[(size_t)c * GCOLS + g2] & kc;
                unsigned long long m = __ballot(w != 0ull);
                if (lane == 0 && m) atomicOr(&dead[g2 >> 6], m);
            }
        }
        __syncthreads();
    }

    if (tid == 0) {
        int pos = 0;
        for (int w = 0; w < NWORDS && pos < NPOST; ++w) {
            unsigned long long kw = keptw[w];
            while (kw && pos < NPOST) {
                int i2 = __builtin_ctzll(kw);
                sel[pos++] = w * 64 + i2;
                kw &= kw - 1;
            }
        }
        for (int w = 0; w < NWORDS && pos < NPOST; ++w) {
            int nvalid = NPRE - w * 64; if (nvalid > 64) nvalid = 64;
            unsigned long long vm = (nvalid >= 64) ? ~0ull : ((1ull << nvalid) - 1ull);
            unsigned long long sw = (~keptw[w]) & vm;
            while (sw && pos < NPOST) {
                int i2 = __builtin_ctzll(sw);
                sel[pos++] = w * 64 + i2;
                sw &= sw - 1;
            }
        }
    }
    __syncthreads();
    for (int s2 = tid; s2 < NPOST; s2 += 1024) {
        int i = sel[s2];
        float4 bx = ((const float4*)bk)[(size_t)b * NPRE + i];
        ((float4*)(out + OUT_ROIS))[b * NPOST + s2] = bx;
        out[OUT_RIDX + b * NPOST + s2] = (float)b;
    }
}

// ---------------- launch ----------------
extern "C" void kernel_launch(void* const* d_in, const int* in_sizes, int n_in,
                              void* d_out, int out_size, void* d_ws, size_t ws_size,
                              hipStream_t stream) {
    const float* x = (const float*)d_in[0];
    const float* conv1_w = (const float*)d_in[1];
    const float* conv1_b = (const float*)d_in[2];
    const float* score_w = (const float*)d_in[3];
    const float* score_b = (const float*)d_in[4];
    const float* loc_w = (const float*)d_in[5];
    const float* loc_b = (const float*)d_in[6];
    const int* ihp = (const int*)d_in[7];
    const int* iwp = (const int*)d_in[8];
    float* out = (float*)d_out;
    char* ws = (char*)d_ws;
    float* h = (float*)(ws + H_OFF);
    float* wT = (float*)(ws + WT_OFF);
    float* boxes = (float*)(ws + BOX_OFF);
    unsigned int* ubuf = (unsigned int*)(ws + U_OFF);
    unsigned long long* ckeys = (unsigned long long*)(ws + CK_OFF);
    unsigned int* cc = (unsigned int*)(ws + CC_OFF);
    float* bk = (float*)(ws + BK_OFF);
    unsigned long long* MT = (unsigned long long*)(ws + M_OFF);

    hipLaunchKernelGGL(k_transpose_w, dim3(2304), dim3(256), 0, stream, conv1_w, wT);
    hipLaunchKernelGGL(k_anchors, dim3(144), dim3(256), 0, stream, out, cc);
    hipLaunchKernelGGL(k_conv1, dim3(8, 8, 8), dim3(512), 0, stream, x, wT, conv1_b, h);
    hipLaunchKernelGGL(k_heads, dim3(32, 8), dim3(256), 0, stream,
                       h, loc_w, score_w, loc_b, score_b, ihp, iwp, out, boxes, ubuf);
    hipLaunchKernelGGL(k_select, dim3(8), dim3(1024), 0, stream, ubuf, ckeys, cc);
    hipLaunchKernelGGL(k_sort, dim3(8), dim3(1024), 0, stream, ckeys, cc, boxes, bk);
    hipLaunchKernelGGL(k_mask, dim3(94, 24, 8), dim3(256), 0, stream, bk, MT);
    hipLaunchKernelGGL(k_nms, dim3(8), dim3(1024), 0, stream, MT, bk, out);
}